// Round 3
// baseline (91.475 us; speedup 1.0000x reference)
//
#include <hip/hip_runtime.h>

// NBCModel: non-backtracking closed-walk signature + MLP.
// B[i,j] = (dst_j == src_i) && (src_j != dst_i).  sig[g,k] = sum over edges i
// in graph g of diag(B^{k+1})_i.  out[g] = relu(sig @ W1 + b1) @ W2 + b2.
//
// R1: per-thread DFS, latency-bound (~105us). R2: level-sync BFS (~40us) —
// residual cost = same-address LDS atomic serialization on the frontier
// counter (return value used -> no wave coalescing) + 5-deep dependent LDS
// chain per expansion. R3: ballot-aggregated reservations (1 atomic/wave/trip),
// 64-bit frontier entries carrying (start, dst_cur, lo, hi) so CSR lookups
// happen at push time, MLP weights staged in LDS.

constexpr int E_EDGES  = 2048;
constexpr int L_WALK   = 8;
constexpr int G_GRAPHS = 128;
constexpr int HID      = 128;
constexpr int N_NODES  = 4096;
constexpr int BLOCK    = 256;
constexpr int CAP      = 4096;   // frontier capacity (expected max level ~1k)

__launch_bounds__(BLOCK, 1)
__global__ void nbc_all(const int* __restrict__ edge_index,
                        const int* __restrict__ edge_graph,
                        const float* __restrict__ W1,
                        const float* __restrict__ b1,
                        const float* __restrict__ W2,
                        const float* __restrict__ b2,
                        float* __restrict__ out)
{
    __shared__ unsigned short s_off[N_NODES + 2]; // CSR offsets (bucket by dst node)
    __shared__ unsigned short s_bucket[E_EDGES];  // edge ids grouped by dst node
    __shared__ unsigned s_srcdst[E_EDGES];        // src | dst<<12
    __shared__ unsigned char s_graph[E_EDGES];    // graph id per edge
    __shared__ int s_sig[G_GRAPHS * L_WALK];      // integer walk counts
    __shared__ unsigned long long s_bufA[CAP];    // frontier ping (low half aliased s_cnt)
    __shared__ unsigned long long s_bufB[CAP];    // frontier pong
    __shared__ int s_nn[L_WALK];                  // frontier size per level
    __shared__ int s_wavep[4];                    // scan partials
    __shared__ float s_W1[L_WALK * HID];
    __shared__ float s_b1[HID];
    __shared__ float s_W2[HID];
    __shared__ float s_b2;

    int* s_cnt = (int*)s_bufA;                    // alias: counts/cursors (4096 ints)

    const int t    = threadIdx.x;
    const int lane = t & 63;
    const int wave = t >> 6;
    const int* src = edge_index;
    const int* dst = edge_index + E_EDGES;

    // ---- init + stage everything into LDS ----
    for (int n = t; n < N_NODES; n += BLOCK) s_cnt[n] = 0;
    for (int n = t; n < G_GRAPHS * L_WALK; n += BLOCK) s_sig[n] = 0;
    if (t < L_WALK) s_nn[t] = 0;
    for (int e = t; e < E_EDGES; e += BLOCK) {
        s_srcdst[e] = (unsigned)src[e] | ((unsigned)dst[e] << 12);
        s_graph[e]  = (unsigned char)edge_graph[e];
    }
    for (int n = t; n < L_WALK * HID; n += BLOCK) s_W1[n] = W1[n];
    if (t < HID) { s_b1[t] = b1[t]; s_W2[t] = W2[t]; }
    if (t == 0) s_b2 = b2[0];
    __syncthreads();

    // ---- count edges per dst node ----
    for (int e = t; e < E_EDGES; e += BLOCK)
        atomicAdd(&s_cnt[s_srcdst[e] >> 12], 1);
    __syncthreads();

    // ---- exclusive scan of 4096 counts -> u16 offsets ----
    const int base16 = t * (N_NODES / BLOCK); // 16 elems/thread
    int loc[16];
    int run = 0;
    #pragma unroll
    for (int j = 0; j < 16; ++j) { loc[j] = run; run += s_cnt[base16 + j]; }
    int incl = run;
    #pragma unroll
    for (int off = 1; off < 64; off <<= 1) {
        int v = __shfl_up(incl, off);
        if (lane >= off) incl += v;
    }
    if (lane == 63) s_wavep[wave] = incl;
    __syncthreads();
    int wbase = 0;
    for (int w = 0; w < wave; ++w) wbase += s_wavep[w];
    const int start = wbase + incl - run;
    #pragma unroll
    for (int j = 0; j < 16; ++j) s_off[base16 + j] = (unsigned short)(start + loc[j]);
    if (t == 0) s_off[N_NODES] = E_EDGES;
    __syncthreads();

    // ---- fill buckets (cursor = copy of offsets, in s_cnt alias) ----
    for (int n = t; n < N_NODES; n += BLOCK) s_cnt[n] = s_off[n];
    __syncthreads();
    for (int e = t; e < E_EDGES; e += BLOCK) {
        int pos = atomicAdd(&s_cnt[s_srcdst[e] >> 12], 1);
        s_bucket[pos] = (unsigned short)e;
    }
    __syncthreads();                 // bucket done; bufA free for frontier

    // Frontier entry (u64): [0:11) start edge s, [11:23) dst of current edge,
    // [23:35) bucket lo of src(current), [35:47) bucket hi.
    // Ballot-aggregated push: one atomicAdd per wave per inner trip.

    // ---- level 0: expand each start edge ----
    for (int i = t; i < E_EDGES; i += BLOCK) {
        unsigned sd = s_srcdst[i];
        int sc  = sd & 0xFFF;
        int dcc = sd >> 12;
        int lo = s_off[sc], hi = s_off[sc + 1];
        for (int p = lo; p < hi; ++p) {
            int b = s_bucket[p];
            unsigned sdb = s_srcdst[b];
            if ((int)(sdb & 0xFFF) != dcc) {       // non-backtracking
                if (b == i) atomicAdd(&s_sig[(int)s_graph[i] * L_WALK + 0], 1);
                int sb = sdb & 0xFFF;
                unsigned long long ent =
                    (unsigned long long)i |
                    ((unsigned long long)(sdb >> 12) << 11) |
                    ((unsigned long long)s_off[sb]     << 23) |
                    ((unsigned long long)s_off[sb + 1] << 35);
                unsigned long long m = __ballot(1);
                int leader = __ffsll(m) - 1;
                int rank   = __popcll(m & ((1ull << lane) - 1ull));
                int bpos = 0;
                if (lane == leader) bpos = atomicAdd(&s_nn[1], (int)__popcll(m));
                bpos = __shfl(bpos, leader);
                int pos = bpos + rank;
                if (pos < CAP) s_bufA[pos] = ent;
            }
        }
    }

    // ---- levels 1..7 ----
    unsigned long long* cur = s_bufA;
    unsigned long long* nxt = s_bufB;
    for (int d = 1; d < L_WALK; ++d) {
        __syncthreads();             // frontier for level d complete
        int n_cur = s_nn[d];
        if (n_cur > CAP) n_cur = CAP;
        for (int idx = t; idx < n_cur; idx += BLOCK) {
            unsigned long long ent = cur[idx];
            int s   =  ent        & 0x7FF;
            int dcc = (ent >> 11) & 0xFFF;
            int lo  = (ent >> 23) & 0xFFF;
            int hi  = (ent >> 35) & 0xFFF;
            for (int p = lo; p < hi; ++p) {
                int b = s_bucket[p];
                unsigned sdb = s_srcdst[b];
                if ((int)(sdb & 0xFFF) != dcc) {
                    if (b == s) atomicAdd(&s_sig[(int)s_graph[s] * L_WALK + d], 1);
                    if (d < L_WALK - 1) {
                        int sb = sdb & 0xFFF;
                        unsigned long long e2 =
                            (unsigned long long)s |
                            ((unsigned long long)(sdb >> 12) << 11) |
                            ((unsigned long long)s_off[sb]     << 23) |
                            ((unsigned long long)s_off[sb + 1] << 35);
                        unsigned long long m = __ballot(1);
                        int leader = __ffsll(m) - 1;
                        int rank   = __popcll(m & ((1ull << lane) - 1ull));
                        int bpos = 0;
                        if (lane == leader) bpos = atomicAdd(&s_nn[d + 1], (int)__popcll(m));
                        bpos = __shfl(bpos, leader);
                        int pos = bpos + rank;
                        if (pos < CAP) nxt[pos] = e2;
                    }
                }
            }
        }
        unsigned long long* tmp = cur; cur = nxt; nxt = tmp;
    }
    __syncthreads();                 // s_sig final

    // ---- MLP: out[g] = relu(sig @ W1 + b1) @ W2 + b2 (weights in LDS) ----
    if (t < G_GRAPHS) {
        float sig[L_WALK];
        #pragma unroll
        for (int k = 0; k < L_WALK; ++k) sig[k] = (float)s_sig[t * L_WALK + k];
        float o = s_b2;
        for (int j = 0; j < HID; ++j) {
            float a = s_b1[j];
            #pragma unroll
            for (int k = 0; k < L_WALK; ++k) a += sig[k] * s_W1[k * HID + j];
            o += fmaxf(a, 0.0f) * s_W2[j];
        }
        out[t] = o;
    }
}

extern "C" void kernel_launch(void* const* d_in, const int* in_sizes, int n_in,
                              void* d_out, int out_size, void* d_ws, size_t ws_size,
                              hipStream_t stream) {
    const int*   edge_index = (const int*)d_in[0];
    const int*   edge_graph = (const int*)d_in[1];
    const float* W1 = (const float*)d_in[2];
    const float* b1 = (const float*)d_in[3];
    const float* W2 = (const float*)d_in[4];
    const float* b2 = (const float*)d_in[5];
    float* out = (float*)d_out;

    nbc_all<<<1, BLOCK, 0, stream>>>(edge_index, edge_graph, W1, b1, W2, b2, out);
}

// Round 4
// 81.415 us; speedup vs baseline: 1.1236x; 1.1236x over previous
//
#include <hip/hip_runtime.h>

// NBCModel: non-backtracking closed-walk signature + MLP.
// B[i,j] = (dst_j == src_i) && (src_j != dst_i).  sig[g,k] = sum over edges i
// in graph g of diag(B^{k+1})_i.  out[g] = relu(sig @ W1 + b1) @ W2 + b2.
//
// R1 DFS ~105us (latency). R2 level-BFS ~38us. R3 ballot atomics: neutral ->
// bottleneck is dependent-LDS-chain latency at 4 waves, not atomic traffic.
// R4: 1024 threads (16 waves); enriched u64 bucket entries so each BFS
// expansion is ONE ds_read_b64 (chain 3 -> 1); uniform levels 0..7 from a
// prebuilt frontier; MLP parallelized 8-way per graph with LDS partials.

constexpr int E_EDGES  = 2048;
constexpr int L_WALK   = 8;
constexpr int G_GRAPHS = 128;
constexpr int HID      = 128;
constexpr int N_NODES  = 4096;
constexpr int BLOCK    = 1024;
constexpr int CAP      = 2048;   // frontier cap; level0 = 2048 exactly, level1 ~1024, shrinking

__launch_bounds__(BLOCK, 1)
__global__ void nbc_all(const int* __restrict__ edge_index,
                        const int* __restrict__ edge_graph,
                        const float* __restrict__ W1,
                        const float* __restrict__ b1,
                        const float* __restrict__ W2,
                        const float* __restrict__ b2,
                        float* __restrict__ out)
{
    // ~63.6 KB static LDS total (under the 64 KB workgroup limit)
    __shared__ unsigned short s_off[N_NODES + 2];      // CSR offsets (bucket by dst)
    __shared__ unsigned long long s_ebucket[E_EDGES];  // b |src<<11 |dst<<23 |lo<<35 |hi<<47
    __shared__ unsigned char s_graph[E_EDGES];         // graph id per edge
    __shared__ int s_sig[G_GRAPHS * L_WALK];           // integer walk counts
    __shared__ unsigned long long s_bufA[CAP];         // frontier ping (aliased s_cnt)
    __shared__ unsigned long long s_bufB[CAP];         // frontier pong
    __shared__ int s_nn[L_WALK + 1];                   // frontier size per level
    __shared__ int s_wavep[16];                        // scan partials

    int* s_cnt = (int*)s_bufA;                         // alias: 4096 counts/cursors

    const int t    = threadIdx.x;
    const int lane = t & 63;
    const int wave = t >> 6;
    const int* src = edge_index;
    const int* dst = edge_index + E_EDGES;

    // ---- zero ----
    for (int n = t; n < N_NODES; n += BLOCK) s_cnt[n] = 0;
    if (t < G_GRAPHS * L_WALK) s_sig[t] = 0;
    if (t <= L_WALK) s_nn[t] = (t == 0) ? E_EDGES : 0;
    __syncthreads();

    // ---- count edges per dst node; stage graph ids ----
    for (int e = t; e < E_EDGES; e += BLOCK) {
        atomicAdd(&s_cnt[dst[e]], 1);
        s_graph[e] = (unsigned char)edge_graph[e];
    }
    __syncthreads();

    // ---- exclusive scan of 4096 counts (4/thread + wave scan + cross-wave) ----
    const int base4 = t * 4;
    int loc[4];
    int run = 0;
    #pragma unroll
    for (int j = 0; j < 4; ++j) { loc[j] = run; run += s_cnt[base4 + j]; }
    int incl = run;
    #pragma unroll
    for (int off = 1; off < 64; off <<= 1) {
        int v = __shfl_up(incl, off);
        if (lane >= off) incl += v;
    }
    if (lane == 63) s_wavep[wave] = incl;
    __syncthreads();
    int wbase = 0;
    for (int w = 0; w < wave; ++w) wbase += s_wavep[w];
    const int start = wbase + incl - run;
    #pragma unroll
    for (int j = 0; j < 4; ++j) s_off[base4 + j] = (unsigned short)(start + loc[j]);
    if (t == 0) s_off[N_NODES] = E_EDGES;
    __syncthreads();

    // ---- cursors = copy of offsets ----
    for (int n = t; n < N_NODES; n += BLOCK) s_cnt[n] = s_off[n];
    __syncthreads();

    // ---- fill enriched bucket: everything an expansion needs in one u64 ----
    for (int e = t; e < E_EDGES; e += BLOCK) {
        int se = src[e], de = dst[e];
        int pos = atomicAdd(&s_cnt[de], 1);
        s_ebucket[pos] = (unsigned long long)e
                       | ((unsigned long long)se << 11)
                       | ((unsigned long long)de << 23)
                       | ((unsigned long long)s_off[se]     << 35)
                       | ((unsigned long long)s_off[se + 1] << 47);
    }
    __syncthreads();

    // ---- level-0 frontier: (s=i, dcc=dst_i, lo=off[src_i], hi) ----
    for (int i = t; i < E_EDGES; i += BLOCK) {
        int se = src[i], de = dst[i];
        s_bufA[i] = (unsigned long long)i
                  | ((unsigned long long)de << 11)
                  | ((unsigned long long)s_off[se]     << 23)
                  | ((unsigned long long)s_off[se + 1] << 35);
    }
    __syncthreads();

    // ---- BFS levels 0..7: one ds_read_b64 per expansion trip ----
    unsigned long long* cur = s_bufA;
    unsigned long long* nxt = s_bufB;
    for (int d = 0; d < L_WALK; ++d) {
        int n_cur = s_nn[d];
        if (n_cur > CAP) n_cur = CAP;
        for (int idx = t; idx < n_cur; idx += BLOCK) {
            unsigned long long e = cur[idx];
            int s   =  e        & 0x7FF;
            int dcc = (e >> 11) & 0xFFF;
            int lo  = (e >> 23) & 0xFFF;
            int hi  = (e >> 35) & 0xFFF;
            for (int p = lo; p < hi; ++p) {
                unsigned long long q = s_ebucket[p];
                int sb = (int)(q >> 11) & 0xFFF;
                if (sb != dcc) {                        // non-backtracking
                    int b = (int)q & 0x7FF;
                    if (b == s) atomicAdd(&s_sig[(int)s_graph[s] * L_WALK + d], 1);
                    if (d < L_WALK - 1) {
                        // next entry: s | dst_b<<11 | lo_b<<23 | hi_b<<35
                        unsigned long long e2 =
                            (unsigned long long)s | (((q >> 23) & 0xFFFFFFFFFull) << 11);
                        unsigned long long m = __ballot(1);
                        int leader = __ffsll(m) - 1;
                        int rank   = __popcll(m & ((1ull << lane) - 1ull));
                        int bpos = 0;
                        if (lane == leader) bpos = atomicAdd(&s_nn[d + 1], (int)__popcll(m));
                        bpos = __shfl(bpos, leader);
                        int pos = bpos + rank;
                        if (pos < CAP) nxt[pos] = e2;
                    }
                }
            }
        }
        unsigned long long* tmp = cur; cur = nxt; nxt = tmp;
        __syncthreads();
    }

    // ---- MLP: 8 threads per graph, 16 hidden cols each; LDS partial sums ----
    float* s_part = (float*)s_ebucket;   // BFS done; reuse 16 KB (need 4 KB)
    {
        const int g   = t >> 3;
        const int sub = t & 7;
        float sig[L_WALK];
        #pragma unroll
        for (int k = 0; k < L_WALK; ++k) sig[k] = (float)s_sig[g * L_WALK + k];
        float o = 0.0f;
        const int j0 = sub * 16;
        #pragma unroll 4
        for (int jj = 0; jj < 16; ++jj) {
            int j = j0 + jj;
            float a = b1[j];
            #pragma unroll
            for (int k = 0; k < L_WALK; ++k) a += sig[k] * W1[k * HID + j];
            o += fmaxf(a, 0.0f) * W2[j];
        }
        s_part[t] = o;
    }
    __syncthreads();
    if (t < G_GRAPHS) {
        float o = b2[0];
        #pragma unroll
        for (int sub = 0; sub < 8; ++sub) o += s_part[t * 8 + sub];
        out[t] = o;
    }
}

extern "C" void kernel_launch(void* const* d_in, const int* in_sizes, int n_in,
                              void* d_out, int out_size, void* d_ws, size_t ws_size,
                              hipStream_t stream) {
    const int*   edge_index = (const int*)d_in[0];
    const int*   edge_graph = (const int*)d_in[1];
    const float* W1 = (const float*)d_in[2];
    const float* b1 = (const float*)d_in[3];
    const float* W2 = (const float*)d_in[4];
    const float* b2 = (const float*)d_in[5];
    float* out = (float*)d_out;

    nbc_all<<<1, BLOCK, 0, stream>>>(edge_index, edge_graph, W1, b1, W2, b2, out);
}